// Round 10
// baseline (210.384 us; speedup 1.0000x reference)
//
#include <hip/hip_runtime.h>
#include <hip/hip_bf16.h>
#include <stdint.h>
#include <math.h>

using bf16x8 = __attribute__((ext_vector_type(8))) short;
using f32x4  = __attribute__((ext_vector_type(4))) float;
using f32x16 = __attribute__((ext_vector_type(16))) float;

#define NHEAD  16
#define DK     64
#define TSEQ   2048
#define DMODEL 1024
#define MTOT   4096   // B*T

// 0.125 (1/sqrt(dk)) * log2(e): folded into Q at the KQV epilogue so the
// flash softmax uses bare exp2.
#define QSCALE 0.18033688011112042f

static __device__ __forceinline__ ushort f2bf(float f) {
  union { float f; uint32_t u; } v; v.f = f;
  return (ushort)((v.u + 0x7FFFu + ((v.u >> 16) & 1u)) >> 16);   // RNE
}

static __device__ __forceinline__ float bf2f(ushort u) {
  union { uint32_t u; float f; } v; v.u = ((uint32_t)u) << 16;
  return v.f;
}

static __device__ __forceinline__ uint32_t cvtpk_bf16(float lo, float hi) {
  uint32_t r;
  asm("v_cvt_pk_bf16_f32 %0, %1, %2" : "=v"(r) : "v"(lo), "v"(hi));
  return r;
}

static __device__ __forceinline__ void gload_lds16(const ushort* g, ushort* l) {
  typedef __attribute__((address_space(1))) const uint32_t gu32;
  typedef __attribute__((address_space(3))) uint32_t lu32;
  __builtin_amdgcn_global_load_lds((gu32*)g, (lu32*)l, 16, 0, 0);
}

// ---------- fused prep: x f32->bf16 (blocks 0..2047) + both W transposes ----------
__global__ __launch_bounds__(256) void prep_kernel(const float* __restrict__ x,
                                                   ushort* __restrict__ x_bf,
                                                   const float* __restrict__ W1,
                                                   ushort* __restrict__ Wt1,
                                                   const float* __restrict__ W2,
                                                   ushort* __restrict__ Wt2) {
  __shared__ ushort tl[64][66];
  const int b = blockIdx.x, tid = threadIdx.x;
  if (b < 2048) {
    const int i = (b * 256 + tid) * 8;
    const float4* p = (const float4*)(x + i);
    float4 a = p[0], bb = p[1];
    bf16x8 v;
    v[0]=(short)f2bf(a.x); v[1]=(short)f2bf(a.y); v[2]=(short)f2bf(a.z); v[3]=(short)f2bf(a.w);
    v[4]=(short)f2bf(bb.x); v[5]=(short)f2bf(bb.y); v[6]=(short)f2bf(bb.z); v[7]=(short)f2bf(bb.w);
    *(bf16x8*)(x_bf + i) = v;
    return;
  }
  const int b2 = b - 2048;                 // [0,1024)
  const int bx = b2 & 63, by = b2 >> 6;    // bx: 48 kqv + 16 wo; by: k0/64
  const float* W; ushort* Wt; int N, n0;
  if (bx < 48) { W = W1; Wt = Wt1; N = 3072; n0 = bx * 64; }
  else         { W = W2; Wt = Wt2; N = 1024; n0 = (bx - 48) * 64; }
  const int k0 = by * 64;
  const int c = tid & 63, r0 = tid >> 6;
#pragma unroll
  for (int i = 0; i < 64; i += 4)
    tl[i + r0][c] = f2bf(W[(size_t)(k0 + i + r0) * N + n0 + c]);
  __syncthreads();
#pragma unroll
  for (int i = 0; i < 64; i += 4)
    Wt[(size_t)(n0 + i + r0) * 1024 + k0 + c] = tl[c][i + r0];
}

// ---------- bf16 GEMM, C = A[M][K] * Bt[N][K]^T + bias, 2-phase dbuf ----------
// MODE 0: scatters K,Q (bf16, Q pre-scaled) into [B,H,T,dk]; V written
//         TRANSPOSED directly to Vt[bh][dk][T] (8B stores, 4 consecutive t).
// MODE 1: fp32 out [M][N]
template <int MODE>
__global__ __launch_bounds__(256, 3)
void gemm_bt_kernel(const ushort* __restrict__ A, const ushort* __restrict__ Bt,
                    const float* __restrict__ bias,
                    ushort* __restrict__ oK, ushort* __restrict__ oQ, ushort* __restrict__ oVt,
                    float* __restrict__ oF, int N, int K) {
  __shared__ ushort As[2][128 * 32];
  __shared__ ushort Bs[2][128 * 32];
  const int tid = threadIdx.x;
  const int w = tid >> 6, lane = tid & 63;
  const int m0 = blockIdx.y * 128, n0 = blockIdx.x * 128;
  const int wr = (w >> 1) * 64, wc = (w & 1) * 64;

  const int e0 = ((w * 2 + 0) * 64 + lane) * 8;
  const int e1 = ((w * 2 + 1) * 64 + lane) * 8;
  const ushort* pA0 = A  + (size_t)(m0 + (e0 >> 5)) * K + (e0 & 31);
  const ushort* pA1 = A  + (size_t)(m0 + (e1 >> 5)) * K + (e1 & 31);
  const ushort* pB0 = Bt + (size_t)(n0 + (e0 >> 5)) * K + (e0 & 31);
  const ushort* pB1 = Bt + (size_t)(n0 + (e1 >> 5)) * K + (e1 & 31);

  f32x4 acc[4][4];
#pragma unroll
  for (int i = 0; i < 4; i++)
#pragma unroll
    for (int j = 0; j < 4; j++) acc[i][j] = (f32x4){0.f, 0.f, 0.f, 0.f};

  const int aro = (wr + (lane & 15)) * 32 + (lane >> 4) * 8;
  const int bro = (wc + (lane & 15)) * 32 + (lane >> 4) * 8;

  // prologue: stage k=0 into buf 0, drain, barrier
  gload_lds16(pA0, &As[0][e0]);
  gload_lds16(pA1, &As[0][e1]);
  gload_lds16(pB0, &Bs[0][e0]);
  gload_lds16(pB1, &Bs[0][e1]);
  asm volatile("s_waitcnt vmcnt(0)" ::: "memory");
  __builtin_amdgcn_s_barrier();

  for (int k0 = 0; k0 < K; k0 += 32) {
    const int cur = (k0 >> 5) & 1;
    if (k0 + 32 < K) {
      const int nb = cur ^ 1, kn = k0 + 32;
      gload_lds16(pA0 + kn, &As[nb][e0]);
      gload_lds16(pA1 + kn, &As[nb][e1]);
      gload_lds16(pB0 + kn, &Bs[nb][e0]);
      gload_lds16(pB1 + kn, &Bs[nb][e1]);
    }
    bf16x8 af[4], bfr[4];
#pragma unroll
    for (int i = 0; i < 4; i++) af[i]  = *(const bf16x8*)&As[cur][aro + i * 16 * 32];
#pragma unroll
    for (int j = 0; j < 4; j++) bfr[j] = *(const bf16x8*)&Bs[cur][bro + j * 16 * 32];
    __builtin_amdgcn_s_setprio(1);
#pragma unroll
    for (int i = 0; i < 4; i++)
#pragma unroll
      for (int j = 0; j < 4; j++)
        acc[i][j] = __builtin_amdgcn_mfma_f32_16x16x32_bf16(af[i], bfr[j], acc[i][j], 0, 0, 0);
    __builtin_amdgcn_s_setprio(0);
    asm volatile("s_waitcnt vmcnt(0)" ::: "memory");
    __builtin_amdgcn_s_barrier();
  }

  const int rbase = m0 + wr + (lane >> 4) * 4;
  const int cbase = n0 + wc + (lane & 15);
#pragma unroll
  for (int i = 0; i < 4; i++) {
#pragma unroll
    for (int j = 0; j < 4; j++) {
      const int gn = cbase + j * 16;
      const float bv = bias[gn];
      if (MODE == 0) {
        const int sel = gn >> 10, cc = gn & 1023;
        const int hh = cc >> 6, dd = cc & 63;
        const int gm0 = rbase + i * 16;
        const int bbx = gm0 >> 11, t0 = gm0 & 2047;
        const int bh = bbx * NHEAD + hh;
        if (sel == 2) {
          // V: write transposed, 4 consecutive t = one 8B store
          const uint32_t lo = (uint32_t)f2bf(acc[i][j][0] + bv) |
                              ((uint32_t)f2bf(acc[i][j][1] + bv) << 16);
          const uint32_t hi = (uint32_t)f2bf(acc[i][j][2] + bv) |
                              ((uint32_t)f2bf(acc[i][j][3] + bv) << 16);
          uint2 pk; pk.x = lo; pk.y = hi;
          *(uint2*)(oVt + ((size_t)bh * DK + dd) * TSEQ + t0) = pk;
        } else {
          ushort* dst = (sel == 0) ? oK : oQ;
          const float sc = (sel == 1) ? QSCALE : 1.0f;
#pragma unroll
          for (int jj = 0; jj < 4; jj++)
            dst[((size_t)bh * TSEQ + t0 + jj) * DK + dd] = f2bf((acc[i][j][jj] + bv) * sc);
        }
      } else {
#pragma unroll
        for (int jj = 0; jj < 4; jj++)
          oF[(size_t)(rbase + i * 16 + jj) * N + gn] = acc[i][j][jj] + bv;
      }
    }
  }
}

// ---------- causal flash attention, swapped-QK^T + chunked split-KV ----------
// 1280 pieces = 32 bh x 40 chunks (<=8 KV-tiles); 4 blocks/CU (round-6 proven).
// This round: tree-reduced row max/sum (depth 5 vs 31-serial chains).
__global__ __launch_bounds__(256, 4)
void attn_kernel(const ushort* __restrict__ Qb, const ushort* __restrict__ Kb,
                 const ushort* __restrict__ Vtb, ushort* __restrict__ Opart,
                 float2* __restrict__ mlbuf) {
  __shared__ ushort Ks[2][64 * 64];    // [kv][dk], XOR-swizzled 16B blocks, dbuf
  __shared__ ushort Vs[2][64 * 64];    // [d][kv], XOR-swizzled, dbuf

  // XCD-grouped mapping (pieces of one bh stay on one XCD); LPT (big qi first)
  const int bid = blockIdx.x;
  const int xcd = bid & 7, i = bid >> 3;            // i in [0,160)
  const int bh = xcd + 8 * (i / 40);
  const int jj = 39 - (i % 40);                     // LPT: decode big pieces first
  int qi, p;
  if (jj < 4)       { qi = jj;                 p = 0; }
  else if (jj < 12) { int t = jj - 4;  qi = 4  + (t >> 1); p = t & 1; }
  else if (jj < 24) { int t = jj - 12; qi = 8  + t / 3;    p = t % 3; }
  else              { int t = jj - 24; qi = 12 + (t >> 2); p = t & 3; }

  const int q0 = qi * 128;
  const int tid = threadIdx.x, w = tid >> 6, lane = tid & 63;
  const int l31 = lane & 31, h = lane >> 5;         // h = wave half
  const int qrow = q0 + w * 32 + l31;               // this lane's q-row

  // piece KV-tile range: [p*8, min(p*8+8, 2qi+2))
  const int t_begin = p * 8;
  const int ntp = min(t_begin + 8, 2 * qi + 2) - t_begin;

  // Q fragments: B-operand of 32x32x16 -> B[n=q=l31][k], 4 dk-slices
  const ushort* Qp = Qb + ((size_t)bh * TSEQ + qrow) * DK;
  bf16x8 qf[4];
#pragma unroll
  for (int c = 0; c < 4; c++)
    qf[c] = *(const bf16x8*)(Qp + c * 16 + h * 8);

  f32x16 oacc0, oacc1;                 // out[d = dh*32 + (r&3)+8*(r>>2)+4h][q=l31]
#pragma unroll
  for (int r = 0; r < 16; r++) { oacc0[r] = 0.f; oacc1[r] = 0.f; }
  float mrun = -INFINITY, lrun = 0.f;  // per-lane = per-q-row (both halves agree)

  // staging: linear LDS dest + inverse-swizzled global source (rule #21)
  const int Bl0 = w * 128 + lane, Bl1 = Bl0 + 64;
  const int sr0 = Bl0 >> 3, sc0 = ((Bl0 & 7) ^ (sr0 & 7)) * 8;
  const int sr1 = Bl1 >> 3, sc1 = ((Bl1 & 7) ^ (sr1 & 7)) * 8;
  const ushort* Kp0 = Kb  + (size_t)bh * TSEQ * DK + sr0 * DK + sc0;
  const ushort* Kp1 = Kb  + (size_t)bh * TSEQ * DK + sr1 * DK + sc1;
  const ushort* Vp0 = Vtb + (size_t)bh * DK * TSEQ + sr0 * TSEQ + sc0;
  const ushort* Vp1 = Vtb + (size_t)bh * DK * TSEQ + sr1 * TSEQ + sc1;

  // prologue: stage tile t_begin into buf 0, drain, barrier
  {
    const int s0 = t_begin * 64;
    gload_lds16(Kp0 + s0 * DK, &Ks[0][Bl0 * 8]);
    gload_lds16(Kp1 + s0 * DK, &Ks[0][Bl1 * 8]);
    gload_lds16(Vp0 + s0, &Vs[0][Bl0 * 8]);
    gload_lds16(Vp1 + s0, &Vs[0][Bl1 * 8]);
  }
  asm volatile("s_waitcnt vmcnt(0)" ::: "memory");
  __builtin_amdgcn_s_barrier();

  for (int tt = 0; tt < ntp; tt++) {
    const int s0 = (t_begin + tt) * 64, cur = tt & 1;

    if (tt + 1 < ntp) {
      const int sn = (t_begin + tt + 1) * 64, nb = cur ^ 1;
      gload_lds16(Kp0 + sn * DK, &Ks[nb][Bl0 * 8]);
      gload_lds16(Kp1 + sn * DK, &Ks[nb][Bl1 * 8]);
      gload_lds16(Vp0 + sn, &Vs[nb][Bl0 * 8]);
      gload_lds16(Vp1 + sn, &Vs[nb][Bl1 * 8]);
    }

    const bool active = (s0 <= q0 + w * 32 + 31);   // wave-uniform
    if (active) {
      // ---- S = K x Q : D[col=q=l31][row=kv_local] ----
      f32x16 ps0, ps1;
#pragma unroll
      for (int r = 0; r < 16; r++) { ps0[r] = 0.f; ps1[r] = 0.f; }
      const char* Kbase = (const char*)&Ks[cur][0];
      __builtin_amdgcn_s_setprio(1);
#pragma unroll
      for (int c = 0; c < 4; c++) {
        const int r0 = l31, r1 = 32 + l31;
        bf16x8 kf0 = *(const bf16x8*)(Kbase + r0 * 128 + ((c * 32 + h * 16) ^ ((r0 & 7) << 4)));
        bf16x8 kf1 = *(const bf16x8*)(Kbase + r1 * 128 + ((c * 32 + h * 16) ^ ((r1 & 7) << 4)));
        ps0 = __builtin_amdgcn_mfma_f32_32x32x16_bf16(kf0, qf[c], ps0, 0, 0, 0);
        ps1 = __builtin_amdgcn_mfma_f32_32x32x16_bf16(kf1, qf[c], ps1, 0, 0, 0);
      }
      __builtin_amdgcn_s_setprio(0);

      // ---- mask (boundary tiles only) ----
      if (s0 + 63 > q0 + w * 32) {
#pragma unroll
        for (int r = 0; r < 16; r++) {
          const int kv0 = s0 + (r & 3) + 8 * (r >> 2) + 4 * h;
          if (kv0 > qrow)      ps0[r] = -INFINITY;
          if (kv0 + 32 > qrow) ps1[r] = -INFINITY;
        }
      }

      // ---- row max: balanced tree (depth 5 + 1 shfl) ----
      float tm[8];
#pragma unroll
      for (int r = 0; r < 8; r++)
        tm[r] = fmaxf(fmaxf(ps0[r], ps0[r + 8]), fmaxf(ps1[r], ps1[r + 8]));
      tm[0] = fmaxf(tm[0], tm[4]); tm[1] = fmaxf(tm[1], tm[5]);
      tm[2] = fmaxf(tm[2], tm[6]); tm[3] = fmaxf(tm[3], tm[7]);
      tm[0] = fmaxf(fmaxf(tm[0], tm[2]), fmaxf(tm[1], tm[3]));
      const float pm = fmaxf(tm[0], __shfl_xor(tm[0], 32));

      // ---- defer-max (T13): rescale only when max grew > 8 (log2 units) ----
      if (!__all(pm <= mrun + 8.0f)) {
        const float nm = fmaxf(mrun, pm);
        const float scl = exp2f(mrun - nm);
        lrun *= scl;
#pragma unroll
        for (int r = 0; r < 16; r++) { oacc0[r] *= scl; oacc1[r] *= scl; }
        mrun = nm;
      }

      // ---- exp2 + row sum (tree) ----
#pragma unroll
      for (int r = 0; r < 16; r++) ps0[r] = exp2f(ps0[r] - mrun);
#pragma unroll
      for (int r = 0; r < 16; r++) ps1[r] = exp2f(ps1[r] - mrun);
      float ts[8];
#pragma unroll
      for (int r = 0; r < 8; r++)
        ts[r] = (ps0[r] + ps0[r + 8]) + (ps1[r] + ps1[r + 8]);
      ts[0] += ts[4]; ts[1] += ts[5]; ts[2] += ts[6]; ts[3] += ts[7];
      ts[0] = (ts[0] + ts[2]) + (ts[1] + ts[3]);
      lrun += ts[0] + __shfl_xor(ts[0], 32);

      // ---- pack P to bf16 words ----
      uint32_t w0[2][4], w1[2][4];
#pragma unroll
      for (int a = 0; a < 4; a++) {
        w0[0][a] = cvtpk_bf16(ps0[4 * a + 0], ps0[4 * a + 1]);
        w1[0][a] = cvtpk_bf16(ps0[4 * a + 2], ps0[4 * a + 3]);
        w0[1][a] = cvtpk_bf16(ps1[4 * a + 0], ps1[4 * a + 1]);
        w1[1][a] = cvtpk_bf16(ps1[4 * a + 2], ps1[4 * a + 3]);
      }

      // ---- PV: per kv-16-slice t=2s+u, build P B-frag via half exchange ----
      const char* Vbase = (const char*)&Vs[cur][0];
#pragma unroll
      for (int s = 0; s < 2; s++) {
#pragma unroll
        for (int u = 0; u < 2; u++) {
          const int t = 2 * s + u;
          const uint32_t sw0 = h ? w0[s][2 * u] : w0[s][2 * u + 1];
          const uint32_t sw1 = h ? w1[s][2 * u] : w1[s][2 * u + 1];
          const uint32_t rx0 = (uint32_t)__shfl_xor((int)sw0, 32);
          const uint32_t rx1 = (uint32_t)__shfl_xor((int)sw1, 32);
          int4 pw;
          pw.x = h ? (int)rx0 : (int)w0[s][2 * u];
          pw.y = h ? (int)rx1 : (int)w1[s][2 * u];
          pw.z = h ? (int)w0[s][2 * u + 1] : (int)rx0;
          pw.w = h ? (int)w1[s][2 * u + 1] : (int)rx1;
          const bf16x8 pf = __builtin_bit_cast(bf16x8, pw);

          const int vr0 = l31, vr1 = 32 + l31;
          bf16x8 vf0 = *(const bf16x8*)(Vbase + vr0 * 128 + ((t * 32 + h * 16) ^ ((vr0 & 7) << 4)));
          bf16x8 vf1 = *(const bf16x8*)(Vbase + vr1 * 128 + ((t * 32 + h * 16) ^ ((vr1 & 7) << 4)));
          __builtin_amdgcn_s_setprio(1);
          oacc0 = __builtin_amdgcn_mfma_f32_32x32x16_bf16(vf0, pf, oacc0, 0, 0, 0);
          oacc1 = __builtin_amdgcn_mfma_f32_32x32x16_bf16(vf1, pf, oacc1, 0, 0, 0);
          __builtin_amdgcn_s_setprio(0);
        }
      }
    }

    asm volatile("s_waitcnt vmcnt(0)" ::: "memory");
    __builtin_amdgcn_s_barrier();
  }

  // ---- write partials: unnormalized O (bf16) + (m, l) ----
  const int partIdx = (bh * 16 + qi) * 4 + p;
  const size_t rowslot = (size_t)partIdx * 128 + (qrow & 127);
  ushort* orow = Opart + rowslot * 64;
#pragma unroll
  for (int r = 0; r < 16; r += 2) {
    const int d0 = (r & 3) + 8 * (r >> 2) + 4 * h;        // even, d1 = d0+1
    const uint32_t v0 = (uint32_t)f2bf(oacc0[r]) | ((uint32_t)f2bf(oacc0[r + 1]) << 16);
    const uint32_t v1 = (uint32_t)f2bf(oacc1[r]) | ((uint32_t)f2bf(oacc1[r + 1]) << 16);
    *(uint32_t*)(orow + d0)      = v0;
    *(uint32_t*)(orow + 32 + d0) = v1;
  }
  if (h == 0) mlbuf[rowslot] = make_float2(mrun, lrun);
}

// ---------- combine np(qi)=qi/4+1 partials: one wave per q-row ----------
__global__ __launch_bounds__(256) void combine_kernel(const ushort* __restrict__ Opart,
                                                      const float2* __restrict__ mlbuf,
                                                      ushort* __restrict__ AO) {
  const int gid = blockIdx.x * 4 + (threadIdx.x >> 6);   // [0, 65536) = bh*2048+q
  const int lane = threadIdx.x & 63;
  const int bh = gid >> 11, q = gid & 2047;
  const int qi = q >> 7, np = (qi >> 2) + 1;
  const size_t base = ((size_t)(bh * 16 + qi) * 4) * 128 + (q & 127);

  float M = -INFINITY;
  for (int p = 0; p < np; p++) M = fmaxf(M, mlbuf[base + (size_t)p * 128].x);
  float den = 0.f, acc = 0.f;
  for (int p = 0; p < np; p++) {
    const float2 ml = mlbuf[base + (size_t)p * 128];
    const float wp = exp2f(ml.x - M);
    den += wp * ml.y;
    acc += wp * bf2f(Opart[(base + (size_t)p * 128) * 64 + lane]);
  }
  const float val = acc / den;
  const int bb = bh >> 4, hd = bh & 15;
  AO[((size_t)bb * TSEQ + q) * DMODEL + hd * DK + lane] = f2bf(val);
}

extern "C" void kernel_launch(void* const* d_in, const int* in_sizes, int n_in,
                              void* d_out, int out_size, void* d_ws, size_t ws_size,
                              hipStream_t stream) {
  (void)in_sizes; (void)n_in; (void)out_size; (void)ws_size;
  const float* x    = (const float*)d_in[0];
  const float* Wkqv = (const float*)d_in[1];
  const float* bkqv = (const float*)d_in[2];
  const float* Wo   = (const float*)d_in[3];
  const float* bo   = (const float*)d_in[4];
  float* out = (float*)d_out;

  char* ws = (char*)d_ws;
  const size_t MB = 1024 * 1024;
  ushort* x_bf   = (ushort*)(ws + 0);        //  8 MB [4096][1024]
  ushort* wkqv_t = (ushort*)(ws + 8 * MB);   //  6 MB [3072][1024]
  ushort* wo_t   = (ushort*)(ws + 14 * MB);  //  2 MB [1024][1024]
  ushort* Kbuf   = (ushort*)(ws + 16 * MB);  //  8 MB [32][2048][64]
  ushort* Qbuf   = (ushort*)(ws + 24 * MB);  //  8 MB (pre-scaled by QSCALE)
  ushort* Vtbuf  = (ushort*)(ws + 32 * MB);  //  8 MB [32][64][2048]
  ushort* AObuf  = (ushort*)(ws + 48 * MB);  //  8 MB [4096][1024]
  ushort* Opart  = (ushort*)(ws + 56 * MB);  // 32 MB [32][16][4][128][64]
  float2* mlbuf  = (float2*)(ws + 88 * MB);  //  2 MB [32][16][4][128]

  prep_kernel<<<3072, 256, 0, stream>>>(x, x_bf, Wkqv, wkqv_t, Wo, wo_t);
  gemm_bt_kernel<0><<<dim3(3072 / 128, 4096 / 128), 256, 0, stream>>>(
      x_bf, wkqv_t, bkqv, Kbuf, Qbuf, Vtbuf, nullptr, 3072, 1024);
  attn_kernel<<<1280, 256, 0, stream>>>(Qbuf, Kbuf, Vtbuf, Opart, mlbuf);
  combine_kernel<<<16384, 256, 0, stream>>>(Opart, mlbuf, AObuf);
  gemm_bt_kernel<1><<<dim3(1024 / 128, 4096 / 128), 256, 0, stream>>>(
      AObuf, wo_t, bo, nullptr, nullptr, nullptr, out, 1024, 1024);
}

// Round 11
// 209.789 us; speedup vs baseline: 1.0028x; 1.0028x over previous
//
#include <hip/hip_runtime.h>
#include <hip/hip_bf16.h>
#include <stdint.h>
#include <math.h>

using bf16x8 = __attribute__((ext_vector_type(8))) short;
using f32x4  = __attribute__((ext_vector_type(4))) float;
using f32x16 = __attribute__((ext_vector_type(16))) float;

#define NHEAD  16
#define DK     64
#define TSEQ   2048
#define DMODEL 1024
#define MTOT   4096   // B*T

// 0.125 (1/sqrt(dk)) * log2(e): folded into Q at the KQV epilogue so the
// flash softmax uses bare exp2.
#define QSCALE 0.18033688011112042f

static __device__ __forceinline__ ushort f2bf(float f) {
  union { float f; uint32_t u; } v; v.f = f;
  return (ushort)((v.u + 0x7FFFu + ((v.u >> 16) & 1u)) >> 16);   // RNE
}

static __device__ __forceinline__ float bf2f(ushort u) {
  union { uint32_t u; float f; } v; v.u = ((uint32_t)u) << 16;
  return v.f;
}

static __device__ __forceinline__ uint32_t cvtpk_bf16(float lo, float hi) {
  uint32_t r;
  asm("v_cvt_pk_bf16_f32 %0, %1, %2" : "=v"(r) : "v"(lo), "v"(hi));
  return r;
}

static __device__ __forceinline__ void gload_lds16(const ushort* g, ushort* l) {
  typedef __attribute__((address_space(1))) const uint32_t gu32;
  typedef __attribute__((address_space(3))) uint32_t lu32;
  __builtin_amdgcn_global_load_lds((gu32*)g, (lu32*)l, 16, 0, 0);
}

// ---------- fused prep: x f32->bf16 (blocks 0..2047) + both W transposes ----------
__global__ __launch_bounds__(256) void prep_kernel(const float* __restrict__ x,
                                                   ushort* __restrict__ x_bf,
                                                   const float* __restrict__ W1,
                                                   ushort* __restrict__ Wt1,
                                                   const float* __restrict__ W2,
                                                   ushort* __restrict__ Wt2) {
  __shared__ ushort tl[64][66];
  const int b = blockIdx.x, tid = threadIdx.x;
  if (b < 2048) {
    const int i = (b * 256 + tid) * 8;
    const float4* p = (const float4*)(x + i);
    float4 a = p[0], bb = p[1];
    bf16x8 v;
    v[0]=(short)f2bf(a.x); v[1]=(short)f2bf(a.y); v[2]=(short)f2bf(a.z); v[3]=(short)f2bf(a.w);
    v[4]=(short)f2bf(bb.x); v[5]=(short)f2bf(bb.y); v[6]=(short)f2bf(bb.z); v[7]=(short)f2bf(bb.w);
    *(bf16x8*)(x_bf + i) = v;
    return;
  }
  const int b2 = b - 2048;                 // [0,1024)
  const int bx = b2 & 63, by = b2 >> 6;    // bx: 48 kqv + 16 wo; by: k0/64
  const float* W; ushort* Wt; int N, n0;
  if (bx < 48) { W = W1; Wt = Wt1; N = 3072; n0 = bx * 64; }
  else         { W = W2; Wt = Wt2; N = 1024; n0 = (bx - 48) * 64; }
  const int k0 = by * 64;
  const int c = tid & 63, r0 = tid >> 6;
#pragma unroll
  for (int i = 0; i < 64; i += 4)
    tl[i + r0][c] = f2bf(W[(size_t)(k0 + i + r0) * N + n0 + c]);
  __syncthreads();
#pragma unroll
  for (int i = 0; i < 64; i += 4)
    Wt[(size_t)(n0 + i + r0) * 1024 + k0 + c] = tl[c][i + r0];
}

// ---------- bf16 GEMM, C = A[M][K] * Bt[N][K]^T + bias ----------
// 3-buffer pipeline with counted vmcnt(4): tile T+2 issued before computing T,
// loads stay in flight across the raw s_barrier (T4 recipe; never drain to 0
// in steady state).
// MODE 0: scatters K,Q (bf16, Q pre-scaled) into [B,H,T,dk]; V written
//         TRANSPOSED directly to Vt[bh][dk][T] (8B stores, 4 consecutive t).
// MODE 1: fp32 out [M][N]
template <int MODE>
__global__ __launch_bounds__(256, 3)
void gemm_bt_kernel(const ushort* __restrict__ A, const ushort* __restrict__ Bt,
                    const float* __restrict__ bias,
                    ushort* __restrict__ oK, ushort* __restrict__ oQ, ushort* __restrict__ oVt,
                    float* __restrict__ oF, int N, int K) {
  __shared__ ushort As[3][128 * 32];
  __shared__ ushort Bs[3][128 * 32];
  const int tid = threadIdx.x;
  const int w = tid >> 6, lane = tid & 63;
  const int m0 = blockIdx.y * 128, n0 = blockIdx.x * 128;
  const int wr = (w >> 1) * 64, wc = (w & 1) * 64;

  const int e0 = ((w * 2 + 0) * 64 + lane) * 8;
  const int e1 = ((w * 2 + 1) * 64 + lane) * 8;
  const ushort* pA0 = A  + (size_t)(m0 + (e0 >> 5)) * K + (e0 & 31);
  const ushort* pA1 = A  + (size_t)(m0 + (e1 >> 5)) * K + (e1 & 31);
  const ushort* pB0 = Bt + (size_t)(n0 + (e0 >> 5)) * K + (e0 & 31);
  const ushort* pB1 = Bt + (size_t)(n0 + (e1 >> 5)) * K + (e1 & 31);

  f32x4 acc[4][4];
#pragma unroll
  for (int i = 0; i < 4; i++)
#pragma unroll
    for (int j = 0; j < 4; j++) acc[i][j] = (f32x4){0.f, 0.f, 0.f, 0.f};

  const int aro = (wr + (lane & 15)) * 32 + (lane >> 4) * 8;
  const int bro = (wc + (lane & 15)) * 32 + (lane >> 4) * 8;

  // prologue: stage tiles 0 and 1; wait tile 0 only (4 newest may remain)
  gload_lds16(pA0, &As[0][e0]);
  gload_lds16(pA1, &As[0][e1]);
  gload_lds16(pB0, &Bs[0][e0]);
  gload_lds16(pB1, &Bs[0][e1]);
  gload_lds16(pA0 + 32, &As[1][e0]);
  gload_lds16(pA1 + 32, &As[1][e1]);
  gload_lds16(pB0 + 32, &Bs[1][e0]);
  gload_lds16(pB1 + 32, &Bs[1][e1]);
  asm volatile("s_waitcnt vmcnt(4)" ::: "memory");
  __builtin_amdgcn_s_barrier();

  for (int k0 = 0; k0 < K; k0 += 32) {
    const int T = k0 >> 5;
    const int cur = T % 3;
    const bool more = (k0 + 64 < K);
    if (more) {
      const int nb = (T + 2) % 3, kn = k0 + 64;
      gload_lds16(pA0 + kn, &As[nb][e0]);
      gload_lds16(pA1 + kn, &As[nb][e1]);
      gload_lds16(pB0 + kn, &Bs[nb][e0]);
      gload_lds16(pB1 + kn, &Bs[nb][e1]);
    }
    bf16x8 af[4], bfr[4];
#pragma unroll
    for (int i = 0; i < 4; i++) af[i]  = *(const bf16x8*)&As[cur][aro + i * 16 * 32];
#pragma unroll
    for (int j = 0; j < 4; j++) bfr[j] = *(const bf16x8*)&Bs[cur][bro + j * 16 * 32];
    __builtin_amdgcn_s_setprio(1);
#pragma unroll
    for (int i = 0; i < 4; i++)
#pragma unroll
      for (int j = 0; j < 4; j++)
        acc[i][j] = __builtin_amdgcn_mfma_f32_16x16x32_bf16(af[i], bfr[j], acc[i][j], 0, 0, 0);
    __builtin_amdgcn_s_setprio(0);
    // counted wait: tile T+1 (older) complete; tile T+2's 4 loads may remain
    if (more) { asm volatile("s_waitcnt vmcnt(4)" ::: "memory"); }
    else      { asm volatile("s_waitcnt vmcnt(0)" ::: "memory"); }
    __builtin_amdgcn_s_barrier();
  }

  const int rbase = m0 + wr + (lane >> 4) * 4;
  const int cbase = n0 + wc + (lane & 15);
#pragma unroll
  for (int i = 0; i < 4; i++) {
#pragma unroll
    for (int j = 0; j < 4; j++) {
      const int gn = cbase + j * 16;
      const float bv = bias[gn];
      if (MODE == 0) {
        const int sel = gn >> 10, cc = gn & 1023;
        const int hh = cc >> 6, dd = cc & 63;
        const int gm0 = rbase + i * 16;
        const int bbx = gm0 >> 11, t0 = gm0 & 2047;
        const int bh = bbx * NHEAD + hh;
        if (sel == 2) {
          // V: write transposed, 4 consecutive t = one 8B store
          const uint32_t lo = (uint32_t)f2bf(acc[i][j][0] + bv) |
                              ((uint32_t)f2bf(acc[i][j][1] + bv) << 16);
          const uint32_t hi = (uint32_t)f2bf(acc[i][j][2] + bv) |
                              ((uint32_t)f2bf(acc[i][j][3] + bv) << 16);
          uint2 pk; pk.x = lo; pk.y = hi;
          *(uint2*)(oVt + ((size_t)bh * DK + dd) * TSEQ + t0) = pk;
        } else {
          ushort* dst = (sel == 0) ? oK : oQ;
          const float sc = (sel == 1) ? QSCALE : 1.0f;
#pragma unroll
          for (int jj = 0; jj < 4; jj++)
            dst[((size_t)bh * TSEQ + t0 + jj) * DK + dd] = f2bf((acc[i][j][jj] + bv) * sc);
        }
      } else {
#pragma unroll
        for (int jj = 0; jj < 4; jj++)
          oF[(size_t)(rbase + i * 16 + jj) * N + gn] = acc[i][j][jj] + bv;
      }
    }
  }
}

// ---------- causal flash attention, swapped-QK^T + chunked split-KV ----------
// 1280 pieces = 32 bh x 40 chunks (<=8 KV-tiles); 4 blocks/CU (round-9 proven).
__global__ __launch_bounds__(256, 4)
void attn_kernel(const ushort* __restrict__ Qb, const ushort* __restrict__ Kb,
                 const ushort* __restrict__ Vtb, ushort* __restrict__ Opart,
                 float2* __restrict__ mlbuf) {
  __shared__ ushort Ks[2][64 * 64];    // [kv][dk], XOR-swizzled 16B blocks, dbuf
  __shared__ ushort Vs[2][64 * 64];    // [d][kv], XOR-swizzled, dbuf

  // XCD-grouped mapping (pieces of one bh stay on one XCD); LPT (big qi first)
  const int bid = blockIdx.x;
  const int xcd = bid & 7, i = bid >> 3;            // i in [0,160)
  const int bh = xcd + 8 * (i / 40);
  const int jj = 39 - (i % 40);                     // LPT: decode big pieces first
  int qi, p;
  if (jj < 4)       { qi = jj;                 p = 0; }
  else if (jj < 12) { int t = jj - 4;  qi = 4  + (t >> 1); p = t & 1; }
  else if (jj < 24) { int t = jj - 12; qi = 8  + t / 3;    p = t % 3; }
  else              { int t = jj - 24; qi = 12 + (t >> 2); p = t & 3; }

  const int q0 = qi * 128;
  const int tid = threadIdx.x, w = tid >> 6, lane = tid & 63;
  const int l31 = lane & 31, h = lane >> 5;         // h = wave half
  const int qrow = q0 + w * 32 + l31;               // this lane's q-row

  // piece KV-tile range: [p*8, min(p*8+8, 2qi+2))
  const int t_begin = p * 8;
  const int ntp = min(t_begin + 8, 2 * qi + 2) - t_begin;

  // Q fragments: B-operand of 32x32x16 -> B[n=q=l31][k], 4 dk-slices
  const ushort* Qp = Qb + ((size_t)bh * TSEQ + qrow) * DK;
  bf16x8 qf[4];
#pragma unroll
  for (int c = 0; c < 4; c++)
    qf[c] = *(const bf16x8*)(Qp + c * 16 + h * 8);

  f32x16 oacc0, oacc1;                 // out[d = dh*32 + (r&3)+8*(r>>2)+4h][q=l31]
#pragma unroll
  for (int r = 0; r < 16; r++) { oacc0[r] = 0.f; oacc1[r] = 0.f; }
  float mrun = -INFINITY, lrun = 0.f;  // per-lane = per-q-row (both halves agree)

  // staging: linear LDS dest + inverse-swizzled global source (rule #21)
  const int Bl0 = w * 128 + lane, Bl1 = Bl0 + 64;
  const int sr0 = Bl0 >> 3, sc0 = ((Bl0 & 7) ^ (sr0 & 7)) * 8;
  const int sr1 = Bl1 >> 3, sc1 = ((Bl1 & 7) ^ (sr1 & 7)) * 8;
  const ushort* Kp0 = Kb  + (size_t)bh * TSEQ * DK + sr0 * DK + sc0;
  const ushort* Kp1 = Kb  + (size_t)bh * TSEQ * DK + sr1 * DK + sc1;
  const ushort* Vp0 = Vtb + (size_t)bh * DK * TSEQ + sr0 * TSEQ + sc0;
  const ushort* Vp1 = Vtb + (size_t)bh * DK * TSEQ + sr1 * TSEQ + sc1;

  // prologue: stage tile t_begin into buf 0, drain, barrier
  {
    const int s0 = t_begin * 64;
    gload_lds16(Kp0 + s0 * DK, &Ks[0][Bl0 * 8]);
    gload_lds16(Kp1 + s0 * DK, &Ks[0][Bl1 * 8]);
    gload_lds16(Vp0 + s0, &Vs[0][Bl0 * 8]);
    gload_lds16(Vp1 + s0, &Vs[0][Bl1 * 8]);
  }
  asm volatile("s_waitcnt vmcnt(0)" ::: "memory");
  __builtin_amdgcn_s_barrier();

  for (int tt = 0; tt < ntp; tt++) {
    const int s0 = (t_begin + tt) * 64, cur = tt & 1;

    if (tt + 1 < ntp) {
      const int sn = (t_begin + tt + 1) * 64, nb = cur ^ 1;
      gload_lds16(Kp0 + sn * DK, &Ks[nb][Bl0 * 8]);
      gload_lds16(Kp1 + sn * DK, &Ks[nb][Bl1 * 8]);
      gload_lds16(Vp0 + sn, &Vs[nb][Bl0 * 8]);
      gload_lds16(Vp1 + sn, &Vs[nb][Bl1 * 8]);
    }

    const bool active = (s0 <= q0 + w * 32 + 31);   // wave-uniform
    if (active) {
      // ---- S = K x Q : D[col=q=l31][row=kv_local] ----
      f32x16 ps0, ps1;
#pragma unroll
      for (int r = 0; r < 16; r++) { ps0[r] = 0.f; ps1[r] = 0.f; }
      const char* Kbase = (const char*)&Ks[cur][0];
      __builtin_amdgcn_s_setprio(1);
#pragma unroll
      for (int c = 0; c < 4; c++) {
        const int r0 = l31, r1 = 32 + l31;
        bf16x8 kf0 = *(const bf16x8*)(Kbase + r0 * 128 + ((c * 32 + h * 16) ^ ((r0 & 7) << 4)));
        bf16x8 kf1 = *(const bf16x8*)(Kbase + r1 * 128 + ((c * 32 + h * 16) ^ ((r1 & 7) << 4)));
        ps0 = __builtin_amdgcn_mfma_f32_32x32x16_bf16(kf0, qf[c], ps0, 0, 0, 0);
        ps1 = __builtin_amdgcn_mfma_f32_32x32x16_bf16(kf1, qf[c], ps1, 0, 0, 0);
      }
      __builtin_amdgcn_s_setprio(0);

      // ---- mask (boundary tiles only) ----
      if (s0 + 63 > q0 + w * 32) {
#pragma unroll
        for (int r = 0; r < 16; r++) {
          const int kv0 = s0 + (r & 3) + 8 * (r >> 2) + 4 * h;
          if (kv0 > qrow)      ps0[r] = -INFINITY;
          if (kv0 + 32 > qrow) ps1[r] = -INFINITY;
        }
      }

      // ---- in-register row max (lane = q-row) ----
      float pm = ps0[0];
#pragma unroll
      for (int r = 1; r < 16; r++) pm = fmaxf(pm, ps0[r]);
#pragma unroll
      for (int r = 0; r < 16; r++) pm = fmaxf(pm, ps1[r]);
      pm = fmaxf(pm, __shfl_xor(pm, 32));

      // ---- defer-max (T13): rescale only when max grew > 8 (log2 units) ----
      if (!__all(pm <= mrun + 8.0f)) {
        const float nm = fmaxf(mrun, pm);
        const float scl = exp2f(mrun - nm);
        lrun *= scl;
#pragma unroll
        for (int r = 0; r < 16; r++) { oacc0[r] *= scl; oacc1[r] *= scl; }
        mrun = nm;
      }

      // ---- exp2 + row sum ----
#pragma unroll
      for (int r = 0; r < 16; r++) ps0[r] = exp2f(ps0[r] - mrun);
#pragma unroll
      for (int r = 0; r < 16; r++) ps1[r] = exp2f(ps1[r] - mrun);
      float rs = 0.f;
#pragma unroll
      for (int r = 0; r < 16; r++) rs += ps0[r] + ps1[r];
      rs += __shfl_xor(rs, 32);
      lrun += rs;

      // ---- pack P to bf16 words ----
      uint32_t w0[2][4], w1[2][4];
#pragma unroll
      for (int a = 0; a < 4; a++) {
        w0[0][a] = cvtpk_bf16(ps0[4 * a + 0], ps0[4 * a + 1]);
        w1[0][a] = cvtpk_bf16(ps0[4 * a + 2], ps0[4 * a + 3]);
        w0[1][a] = cvtpk_bf16(ps1[4 * a + 0], ps1[4 * a + 1]);
        w1[1][a] = cvtpk_bf16(ps1[4 * a + 2], ps1[4 * a + 3]);
      }

      // ---- PV: per kv-16-slice t=2s+u, build P B-frag via half exchange ----
      const char* Vbase = (const char*)&Vs[cur][0];
#pragma unroll
      for (int s = 0; s < 2; s++) {
#pragma unroll
        for (int u = 0; u < 2; u++) {
          const int t = 2 * s + u;
          const uint32_t sw0 = h ? w0[s][2 * u] : w0[s][2 * u + 1];
          const uint32_t sw1 = h ? w1[s][2 * u] : w1[s][2 * u + 1];
          const uint32_t rx0 = (uint32_t)__shfl_xor((int)sw0, 32);
          const uint32_t rx1 = (uint32_t)__shfl_xor((int)sw1, 32);
          int4 pw;
          pw.x = h ? (int)rx0 : (int)w0[s][2 * u];
          pw.y = h ? (int)rx1 : (int)w1[s][2 * u];
          pw.z = h ? (int)w0[s][2 * u + 1] : (int)rx0;
          pw.w = h ? (int)w1[s][2 * u + 1] : (int)rx1;
          const bf16x8 pf = __builtin_bit_cast(bf16x8, pw);

          const int vr0 = l31, vr1 = 32 + l31;
          bf16x8 vf0 = *(const bf16x8*)(Vbase + vr0 * 128 + ((t * 32 + h * 16) ^ ((vr0 & 7) << 4)));
          bf16x8 vf1 = *(const bf16x8*)(Vbase + vr1 * 128 + ((t * 32 + h * 16) ^ ((vr1 & 7) << 4)));
          __builtin_amdgcn_s_setprio(1);
          oacc0 = __builtin_amdgcn_mfma_f32_32x32x16_bf16(vf0, pf, oacc0, 0, 0, 0);
          oacc1 = __builtin_amdgcn_mfma_f32_32x32x16_bf16(vf1, pf, oacc1, 0, 0, 0);
          __builtin_amdgcn_s_setprio(0);
        }
      }
    }

    asm volatile("s_waitcnt vmcnt(0)" ::: "memory");
    __builtin_amdgcn_s_barrier();
  }

  // ---- write partials: unnormalized O (bf16) + (m, l) ----
  const int partIdx = (bh * 16 + qi) * 4 + p;
  const size_t rowslot = (size_t)partIdx * 128 + (qrow & 127);
  ushort* orow = Opart + rowslot * 64;
#pragma unroll
  for (int r = 0; r < 16; r += 2) {
    const int d0 = (r & 3) + 8 * (r >> 2) + 4 * h;        // even, d1 = d0+1
    const uint32_t v0 = (uint32_t)f2bf(oacc0[r]) | ((uint32_t)f2bf(oacc0[r + 1]) << 16);
    const uint32_t v1 = (uint32_t)f2bf(oacc1[r]) | ((uint32_t)f2bf(oacc1[r + 1]) << 16);
    *(uint32_t*)(orow + d0)      = v0;
    *(uint32_t*)(orow + 32 + d0) = v1;
  }
  if (h == 0) mlbuf[rowslot] = make_float2(mrun, lrun);
}

// ---------- combine np(qi)=qi/4+1 partials: one wave per q-row ----------
__global__ __launch_bounds__(256) void combine_kernel(const ushort* __restrict__ Opart,
                                                      const float2* __restrict__ mlbuf,
                                                      ushort* __restrict__ AO) {
  const int gid = blockIdx.x * 4 + (threadIdx.x >> 6);   // [0, 65536) = bh*2048+q
  const int lane = threadIdx.x & 63;
  const int bh = gid >> 11, q = gid & 2047;
  const int qi = q >> 7, np = (qi >> 2) + 1;
  const size_t base = ((size_t)(bh * 16 + qi) * 4) * 128 + (q & 127);

  float M = -INFINITY;
  for (int p = 0; p < np; p++) M = fmaxf(M, mlbuf[base + (size_t)p * 128].x);
  float den = 0.f, acc = 0.f;
  for (int p = 0; p < np; p++) {
    const float2 ml = mlbuf[base + (size_t)p * 128];
    const float wp = exp2f(ml.x - M);
    den += wp * ml.y;
    acc += wp * bf2f(Opart[(base + (size_t)p * 128) * 64 + lane]);
  }
  const float val = acc / den;
  const int bb = bh >> 4, hd = bh & 15;
  AO[((size_t)bb * TSEQ + q) * DMODEL + hd * DK + lane] = f2bf(val);
}

extern "C" void kernel_launch(void* const* d_in, const int* in_sizes, int n_in,
                              void* d_out, int out_size, void* d_ws, size_t ws_size,
                              hipStream_t stream) {
  (void)in_sizes; (void)n_in; (void)out_size; (void)ws_size;
  const float* x    = (const float*)d_in[0];
  const float* Wkqv = (const float*)d_in[1];
  const float* bkqv = (const float*)d_in[2];
  const float* Wo   = (const float*)d_in[3];
  const float* bo   = (const float*)d_in[4];
  float* out = (float*)d_out;

  char* ws = (char*)d_ws;
  const size_t MB = 1024 * 1024;
  ushort* x_bf   = (ushort*)(ws + 0);        //  8 MB [4096][1024]
  ushort* wkqv_t = (ushort*)(ws + 8 * MB);   //  6 MB [3072][1024]
  ushort* wo_t   = (ushort*)(ws + 14 * MB);  //  2 MB [1024][1024]
  ushort* Kbuf   = (ushort*)(ws + 16 * MB);  //  8 MB [32][2048][64]
  ushort* Qbuf   = (ushort*)(ws + 24 * MB);  //  8 MB (pre-scaled by QSCALE)
  ushort* Vtbuf  = (ushort*)(ws + 32 * MB);  //  8 MB [32][64][2048]
  ushort* AObuf  = (ushort*)(ws + 48 * MB);  //  8 MB [4096][1024]
  ushort* Opart  = (ushort*)(ws + 56 * MB);  // 32 MB [32][16][4][128][64]
  float2* mlbuf  = (float2*)(ws + 88 * MB);  //  2 MB [32][16][4][128]

  prep_kernel<<<3072, 256, 0, stream>>>(x, x_bf, Wkqv, wkqv_t, Wo, wo_t);
  gemm_bt_kernel<0><<<dim3(3072 / 128, 4096 / 128), 256, 0, stream>>>(
      x_bf, wkqv_t, bkqv, Kbuf, Qbuf, Vtbuf, nullptr, 3072, 1024);
  attn_kernel<<<1280, 256, 0, stream>>>(Qbuf, Kbuf, Vtbuf, Opart, mlbuf);
  combine_kernel<<<16384, 256, 0, stream>>>(Opart, mlbuf, AObuf);
  gemm_bt_kernel<1><<<dim3(1024 / 128, 4096 / 128), 256, 0, stream>>>(
      AObuf, wo_t, bo, nullptr, nullptr, nullptr, out, 1024, 1024);
}

// Round 12
// 207.312 us; speedup vs baseline: 1.0148x; 1.0120x over previous
//
#include <hip/hip_runtime.h>
#include <hip/hip_bf16.h>
#include <stdint.h>
#include <math.h>

using bf16x8 = __attribute__((ext_vector_type(8))) short;
using f32x4  = __attribute__((ext_vector_type(4))) float;
using f32x16 = __attribute__((ext_vector_type(16))) float;

#define NHEAD  16
#define DK     64
#define TSEQ   2048
#define DMODEL 1024
#define MTOT   4096   // B*T

// 0.125 (1/sqrt(dk)) * log2(e): folded into Q at the KQV epilogue so the
// flash softmax uses bare exp2.
#define QSCALE 0.18033688011112042f

static __device__ __forceinline__ ushort f2bf(float f) {
  union { float f; uint32_t u; } v; v.f = f;
  return (ushort)((v.u + 0x7FFFu + ((v.u >> 16) & 1u)) >> 16);   // RNE
}

static __device__ __forceinline__ float bf2f(ushort u) {
  union { uint32_t u; float f; } v; v.u = ((uint32_t)u) << 16;
  return v.f;
}

static __device__ __forceinline__ uint32_t cvtpk_bf16(float lo, float hi) {
  uint32_t r;
  asm("v_cvt_pk_bf16_f32 %0, %1, %2" : "=v"(r) : "v"(lo), "v"(hi));
  return r;
}

static __device__ __forceinline__ void gload_lds16(const ushort* g, ushort* l) {
  typedef __attribute__((address_space(1))) const uint32_t gu32;
  typedef __attribute__((address_space(3))) uint32_t lu32;
  __builtin_amdgcn_global_load_lds((gu32*)g, (lu32*)l, 16, 0, 0);
}

// ---------- fused prep: x f32->bf16 (blocks 0..2047) + both W transposes ----------
__global__ __launch_bounds__(256) void prep_kernel(const float* __restrict__ x,
                                                   ushort* __restrict__ x_bf,
                                                   const float* __restrict__ W1,
                                                   ushort* __restrict__ Wt1,
                                                   const float* __restrict__ W2,
                                                   ushort* __restrict__ Wt2) {
  __shared__ ushort tl[64][66];
  const int b = blockIdx.x, tid = threadIdx.x;
  if (b < 2048) {
    const int i = (b * 256 + tid) * 8;
    const float4* p = (const float4*)(x + i);
    float4 a = p[0], bb = p[1];
    bf16x8 v;
    v[0]=(short)f2bf(a.x); v[1]=(short)f2bf(a.y); v[2]=(short)f2bf(a.z); v[3]=(short)f2bf(a.w);
    v[4]=(short)f2bf(bb.x); v[5]=(short)f2bf(bb.y); v[6]=(short)f2bf(bb.z); v[7]=(short)f2bf(bb.w);
    *(bf16x8*)(x_bf + i) = v;
    return;
  }
  const int b2 = b - 2048;                 // [0,1024)
  const int bx = b2 & 63, by = b2 >> 6;    // bx: 48 kqv + 16 wo; by: k0/64
  const float* W; ushort* Wt; int N, n0;
  if (bx < 48) { W = W1; Wt = Wt1; N = 3072; n0 = bx * 64; }
  else         { W = W2; Wt = Wt2; N = 1024; n0 = (bx - 48) * 64; }
  const int k0 = by * 64;
  const int c = tid & 63, r0 = tid >> 6;
#pragma unroll
  for (int i = 0; i < 64; i += 4)
    tl[i + r0][c] = f2bf(W[(size_t)(k0 + i + r0) * N + n0 + c]);
  __syncthreads();
#pragma unroll
  for (int i = 0; i < 64; i += 4)
    Wt[(size_t)(n0 + i + r0) * 1024 + k0 + c] = tl[c][i + r0];
}

// ---------- bf16 GEMM, C = A[M][K] * Bt[N][K]^T + bias ----------
// 3-buffer pipeline with counted vmcnt: tile T+2 issued before computing T.
// MODE 0: BM=128, 3 blocks/CU; scatters K,Q (Q pre-scaled) into [B,H,T,dk];
//         V written TRANSPOSED to Vt[bh][dk][T].
// MODE 1: BM=64 (grid 512 = 2/CU for the N=1024 projection); fp32 out [M][N].
template <int MODE>
__global__ __launch_bounds__(256, (MODE == 0) ? 3 : 4)
void gemm_bt_kernel(const ushort* __restrict__ A, const ushort* __restrict__ Bt,
                    const float* __restrict__ bias,
                    ushort* __restrict__ oK, ushort* __restrict__ oQ, ushort* __restrict__ oVt,
                    float* __restrict__ oF, int N, int K) {
  constexpr int BM = (MODE == 0) ? 128 : 64;
  constexpr int NLD = (MODE == 0) ? 4 : 3;     // gloads per thread per K-step
  __shared__ ushort As[3][BM * 32];
  __shared__ ushort Bs[3][128 * 32];
  const int tid = threadIdx.x;
  const int w = tid >> 6, lane = tid & 63;
  const int m0 = blockIdx.y * BM, n0 = blockIdx.x * 128;
  const int l15 = lane & 15, l4 = lane >> 4;
  const int wr = (MODE == 0) ? ((w >> 1) * 64) : ((w >> 1) * 32);
  const int wc = (w & 1) * 64;
  constexpr int MI = (MODE == 0) ? 4 : 2;      // row frags per wave

  // staging chunk geometry (16B chunks, LDS linear)
  const int eA0 = tid * 8;                      // A chunk 0 (all MODEs)
  const int eA1 = (tid + 256) * 8;              // A chunk 1 (MODE 0 only)
  const int eB0 = tid * 8, eB1 = (tid + 256) * 8;
  const ushort* pA0 = A  + (size_t)(m0 + (eA0 >> 5)) * K + (eA0 & 31);
  const ushort* pA1 = A  + (size_t)(m0 + (eA1 >> 5)) * K + (eA1 & 31);
  const ushort* pB0 = Bt + (size_t)(n0 + (eB0 >> 5)) * K + (eB0 & 31);
  const ushort* pB1 = Bt + (size_t)(n0 + (eB1 >> 5)) * K + (eB1 & 31);

  f32x4 acc[MI][4];
#pragma unroll
  for (int i = 0; i < MI; i++)
#pragma unroll
    for (int j = 0; j < 4; j++) acc[i][j] = (f32x4){0.f, 0.f, 0.f, 0.f};

  const int aro = (wr + l15) * 32 + l4 * 8;
  const int bro = (wc + l15) * 32 + l4 * 8;

  // prologue: stage tiles 0 and 1; wait tile 0 only (NLD newest may remain)
#pragma unroll
  for (int t = 0; t < 2; t++) {
    gload_lds16(pA0 + t * 32, &As[t][eA0]);
    if (MODE == 0) gload_lds16(pA1 + t * 32, &As[t][eA1]);
    gload_lds16(pB0 + t * 32, &Bs[t][eB0]);
    gload_lds16(pB1 + t * 32, &Bs[t][eB1]);
  }
  if (MODE == 0) { asm volatile("s_waitcnt vmcnt(4)" ::: "memory"); }
  else           { asm volatile("s_waitcnt vmcnt(3)" ::: "memory"); }
  __builtin_amdgcn_s_barrier();

  for (int k0 = 0; k0 < K; k0 += 32) {
    const int T = k0 >> 5;
    const int cur = T % 3;
    const bool more = (k0 + 64 < K);
    if (more) {
      const int nb = (T + 2) % 3, kn = k0 + 64;
      gload_lds16(pA0 + kn, &As[nb][eA0]);
      if (MODE == 0) gload_lds16(pA1 + kn, &As[nb][eA1]);
      gload_lds16(pB0 + kn, &Bs[nb][eB0]);
      gload_lds16(pB1 + kn, &Bs[nb][eB1]);
    }
    bf16x8 af[MI], bfr[4];
#pragma unroll
    for (int i = 0; i < MI; i++) af[i]  = *(const bf16x8*)&As[cur][aro + i * 16 * 32];
#pragma unroll
    for (int j = 0; j < 4; j++) bfr[j] = *(const bf16x8*)&Bs[cur][bro + j * 16 * 32];
    __builtin_amdgcn_s_setprio(1);
#pragma unroll
    for (int i = 0; i < MI; i++)
#pragma unroll
      for (int j = 0; j < 4; j++)
        acc[i][j] = __builtin_amdgcn_mfma_f32_16x16x32_bf16(af[i], bfr[j], acc[i][j], 0, 0, 0);
    __builtin_amdgcn_s_setprio(0);
    // counted wait: tile T+1 (older) complete; tile T+2's loads may remain
    if (more) {
      if (MODE == 0) { asm volatile("s_waitcnt vmcnt(4)" ::: "memory"); }
      else           { asm volatile("s_waitcnt vmcnt(3)" ::: "memory"); }
    } else {
      asm volatile("s_waitcnt vmcnt(0)" ::: "memory");
    }
    __builtin_amdgcn_s_barrier();
  }

  const int rbase = m0 + wr + l4 * 4;
  const int cbase = n0 + wc + l15;
#pragma unroll
  for (int i = 0; i < MI; i++) {
#pragma unroll
    for (int j = 0; j < 4; j++) {
      const int gn = cbase + j * 16;
      const float bv = bias[gn];
      if (MODE == 0) {
        const int sel = gn >> 10, cc = gn & 1023;
        const int hh = cc >> 6, dd = cc & 63;
        const int gm0 = rbase + i * 16;
        const int bbx = gm0 >> 11, t0 = gm0 & 2047;
        const int bh = bbx * NHEAD + hh;
        if (sel == 2) {
          // V: write transposed, 4 consecutive t = one 8B store
          const uint32_t lo = (uint32_t)f2bf(acc[i][j][0] + bv) |
                              ((uint32_t)f2bf(acc[i][j][1] + bv) << 16);
          const uint32_t hi = (uint32_t)f2bf(acc[i][j][2] + bv) |
                              ((uint32_t)f2bf(acc[i][j][3] + bv) << 16);
          uint2 pk; pk.x = lo; pk.y = hi;
          *(uint2*)(oVt + ((size_t)bh * DK + dd) * TSEQ + t0) = pk;
        } else {
          ushort* dst = (sel == 0) ? oK : oQ;
          const float sc = (sel == 1) ? QSCALE : 1.0f;
#pragma unroll
          for (int jj = 0; jj < 4; jj++)
            dst[((size_t)bh * TSEQ + t0 + jj) * DK + dd] = f2bf((acc[i][j][jj] + bv) * sc);
        }
      } else {
#pragma unroll
        for (int jj = 0; jj < 4; jj++)
          oF[(size_t)(rbase + i * 16 + jj) * N + gn] = acc[i][j][jj] + bv;
      }
    }
  }
}

// ---------- causal flash attention, swapped-QK^T + chunked split-KV ----------
// 1280 pieces = 32 bh x 40 chunks (<=8 KV-tiles); 4 blocks/CU (round-9 proven).
__global__ __launch_bounds__(256, 4)
void attn_kernel(const ushort* __restrict__ Qb, const ushort* __restrict__ Kb,
                 const ushort* __restrict__ Vtb, ushort* __restrict__ Opart,
                 float2* __restrict__ mlbuf) {
  __shared__ ushort Ks[2][64 * 64];    // [kv][dk], XOR-swizzled 16B blocks, dbuf
  __shared__ ushort Vs[2][64 * 64];    // [d][kv], XOR-swizzled, dbuf

  // XCD-grouped mapping (pieces of one bh stay on one XCD); LPT (big qi first)
  const int bid = blockIdx.x;
  const int xcd = bid & 7, i = bid >> 3;            // i in [0,160)
  const int bh = xcd + 8 * (i / 40);
  const int jj = 39 - (i % 40);                     // LPT: decode big pieces first
  int qi, p;
  if (jj < 4)       { qi = jj;                 p = 0; }
  else if (jj < 12) { int t = jj - 4;  qi = 4  + (t >> 1); p = t & 1; }
  else if (jj < 24) { int t = jj - 12; qi = 8  + t / 3;    p = t % 3; }
  else              { int t = jj - 24; qi = 12 + (t >> 2); p = t & 3; }

  const int q0 = qi * 128;
  const int tid = threadIdx.x, w = tid >> 6, lane = tid & 63;
  const int l31 = lane & 31, h = lane >> 5;         // h = wave half
  const int qrow = q0 + w * 32 + l31;               // this lane's q-row

  // piece KV-tile range: [p*8, min(p*8+8, 2qi+2))
  const int t_begin = p * 8;
  const int ntp = min(t_begin + 8, 2 * qi + 2) - t_begin;

  // Q fragments: B-operand of 32x32x16 -> B[n=q=l31][k], 4 dk-slices
  const ushort* Qp = Qb + ((size_t)bh * TSEQ + qrow) * DK;
  bf16x8 qf[4];
#pragma unroll
  for (int c = 0; c < 4; c++)
    qf[c] = *(const bf16x8*)(Qp + c * 16 + h * 8);

  f32x16 oacc0, oacc1;                 // out[d = dh*32 + (r&3)+8*(r>>2)+4h][q=l31]
#pragma unroll
  for (int r = 0; r < 16; r++) { oacc0[r] = 0.f; oacc1[r] = 0.f; }
  float mrun = -INFINITY, lrun = 0.f;  // per-lane = per-q-row (both halves agree)

  // staging: linear LDS dest + inverse-swizzled global source (rule #21)
  const int Bl0 = w * 128 + lane, Bl1 = Bl0 + 64;
  const int sr0 = Bl0 >> 3, sc0 = ((Bl0 & 7) ^ (sr0 & 7)) * 8;
  const int sr1 = Bl1 >> 3, sc1 = ((Bl1 & 7) ^ (sr1 & 7)) * 8;
  const ushort* Kp0 = Kb  + (size_t)bh * TSEQ * DK + sr0 * DK + sc0;
  const ushort* Kp1 = Kb  + (size_t)bh * TSEQ * DK + sr1 * DK + sc1;
  const ushort* Vp0 = Vtb + (size_t)bh * DK * TSEQ + sr0 * TSEQ + sc0;
  const ushort* Vp1 = Vtb + (size_t)bh * DK * TSEQ + sr1 * TSEQ + sc1;

  // prologue: stage tile t_begin into buf 0, drain, barrier
  {
    const int s0 = t_begin * 64;
    gload_lds16(Kp0 + s0 * DK, &Ks[0][Bl0 * 8]);
    gload_lds16(Kp1 + s0 * DK, &Ks[0][Bl1 * 8]);
    gload_lds16(Vp0 + s0, &Vs[0][Bl0 * 8]);
    gload_lds16(Vp1 + s0, &Vs[0][Bl1 * 8]);
  }
  asm volatile("s_waitcnt vmcnt(0)" ::: "memory");
  __builtin_amdgcn_s_barrier();

  for (int tt = 0; tt < ntp; tt++) {
    const int s0 = (t_begin + tt) * 64, cur = tt & 1;

    if (tt + 1 < ntp) {
      const int sn = (t_begin + tt + 1) * 64, nb = cur ^ 1;
      gload_lds16(Kp0 + sn * DK, &Ks[nb][Bl0 * 8]);
      gload_lds16(Kp1 + sn * DK, &Ks[nb][Bl1 * 8]);
      gload_lds16(Vp0 + sn, &Vs[nb][Bl0 * 8]);
      gload_lds16(Vp1 + sn, &Vs[nb][Bl1 * 8]);
    }

    const bool active = (s0 <= q0 + w * 32 + 31);   // wave-uniform
    if (active) {
      // ---- S = K x Q : D[col=q=l31][row=kv_local] ----
      f32x16 ps0, ps1;
#pragma unroll
      for (int r = 0; r < 16; r++) { ps0[r] = 0.f; ps1[r] = 0.f; }
      const char* Kbase = (const char*)&Ks[cur][0];
      __builtin_amdgcn_s_setprio(1);
#pragma unroll
      for (int c = 0; c < 4; c++) {
        const int r0 = l31, r1 = 32 + l31;
        bf16x8 kf0 = *(const bf16x8*)(Kbase + r0 * 128 + ((c * 32 + h * 16) ^ ((r0 & 7) << 4)));
        bf16x8 kf1 = *(const bf16x8*)(Kbase + r1 * 128 + ((c * 32 + h * 16) ^ ((r1 & 7) << 4)));
        ps0 = __builtin_amdgcn_mfma_f32_32x32x16_bf16(kf0, qf[c], ps0, 0, 0, 0);
        ps1 = __builtin_amdgcn_mfma_f32_32x32x16_bf16(kf1, qf[c], ps1, 0, 0, 0);
      }
      __builtin_amdgcn_s_setprio(0);

      // ---- mask (boundary tiles only) ----
      if (s0 + 63 > q0 + w * 32) {
#pragma unroll
        for (int r = 0; r < 16; r++) {
          const int kv0 = s0 + (r & 3) + 8 * (r >> 2) + 4 * h;
          if (kv0 > qrow)      ps0[r] = -INFINITY;
          if (kv0 + 32 > qrow) ps1[r] = -INFINITY;
        }
      }

      // ---- in-register row max (lane = q-row) ----
      float pm = ps0[0];
#pragma unroll
      for (int r = 1; r < 16; r++) pm = fmaxf(pm, ps0[r]);
#pragma unroll
      for (int r = 0; r < 16; r++) pm = fmaxf(pm, ps1[r]);
      pm = fmaxf(pm, __shfl_xor(pm, 32));

      // ---- defer-max (T13): rescale only when max grew > 8 (log2 units) ----
      if (!__all(pm <= mrun + 8.0f)) {
        const float nm = fmaxf(mrun, pm);
        const float scl = exp2f(mrun - nm);
        lrun *= scl;
#pragma unroll
        for (int r = 0; r < 16; r++) { oacc0[r] *= scl; oacc1[r] *= scl; }
        mrun = nm;
      }

      // ---- exp2 + row sum ----
#pragma unroll
      for (int r = 0; r < 16; r++) ps0[r] = exp2f(ps0[r] - mrun);
#pragma unroll
      for (int r = 0; r < 16; r++) ps1[r] = exp2f(ps1[r] - mrun);
      float rs = 0.f;
#pragma unroll
      for (int r = 0; r < 16; r++) rs += ps0[r] + ps1[r];
      rs += __shfl_xor(rs, 32);
      lrun += rs;

      // ---- pack P to bf16 words ----
      uint32_t w0[2][4], w1[2][4];
#pragma unroll
      for (int a = 0; a < 4; a++) {
        w0[0][a] = cvtpk_bf16(ps0[4 * a + 0], ps0[4 * a + 1]);
        w1[0][a] = cvtpk_bf16(ps0[4 * a + 2], ps0[4 * a + 3]);
        w0[1][a] = cvtpk_bf16(ps1[4 * a + 0], ps1[4 * a + 1]);
        w1[1][a] = cvtpk_bf16(ps1[4 * a + 2], ps1[4 * a + 3]);
      }

      // ---- PV: per kv-16-slice t=2s+u, build P B-frag via half exchange ----
      const char* Vbase = (const char*)&Vs[cur][0];
#pragma unroll
      for (int s = 0; s < 2; s++) {
#pragma unroll
        for (int u = 0; u < 2; u++) {
          const int t = 2 * s + u;
          const uint32_t sw0 = h ? w0[s][2 * u] : w0[s][2 * u + 1];
          const uint32_t sw1 = h ? w1[s][2 * u] : w1[s][2 * u + 1];
          const uint32_t rx0 = (uint32_t)__shfl_xor((int)sw0, 32);
          const uint32_t rx1 = (uint32_t)__shfl_xor((int)sw1, 32);
          int4 pw;
          pw.x = h ? (int)rx0 : (int)w0[s][2 * u];
          pw.y = h ? (int)rx1 : (int)w1[s][2 * u];
          pw.z = h ? (int)w0[s][2 * u + 1] : (int)rx0;
          pw.w = h ? (int)w1[s][2 * u + 1] : (int)rx1;
          const bf16x8 pf = __builtin_bit_cast(bf16x8, pw);

          const int vr0 = l31, vr1 = 32 + l31;
          bf16x8 vf0 = *(const bf16x8*)(Vbase + vr0 * 128 + ((t * 32 + h * 16) ^ ((vr0 & 7) << 4)));
          bf16x8 vf1 = *(const bf16x8*)(Vbase + vr1 * 128 + ((t * 32 + h * 16) ^ ((vr1 & 7) << 4)));
          __builtin_amdgcn_s_setprio(1);
          oacc0 = __builtin_amdgcn_mfma_f32_32x32x16_bf16(vf0, pf, oacc0, 0, 0, 0);
          oacc1 = __builtin_amdgcn_mfma_f32_32x32x16_bf16(vf1, pf, oacc1, 0, 0, 0);
          __builtin_amdgcn_s_setprio(0);
        }
      }
    }

    asm volatile("s_waitcnt vmcnt(0)" ::: "memory");
    __builtin_amdgcn_s_barrier();
  }

  // ---- write partials: unnormalized O (bf16) + (m, l) ----
  const int partIdx = (bh * 16 + qi) * 4 + p;
  const size_t rowslot = (size_t)partIdx * 128 + (qrow & 127);
  ushort* orow = Opart + rowslot * 64;
#pragma unroll
  for (int r = 0; r < 16; r += 2) {
    const int d0 = (r & 3) + 8 * (r >> 2) + 4 * h;        // even, d1 = d0+1
    const uint32_t v0 = (uint32_t)f2bf(oacc0[r]) | ((uint32_t)f2bf(oacc0[r + 1]) << 16);
    const uint32_t v1 = (uint32_t)f2bf(oacc1[r]) | ((uint32_t)f2bf(oacc1[r + 1]) << 16);
    *(uint32_t*)(orow + d0)      = v0;
    *(uint32_t*)(orow + 32 + d0) = v1;
  }
  if (h == 0) mlbuf[rowslot] = make_float2(mrun, lrun);
}

// ---------- combine np(qi)=qi/4+1 partials: one wave per q-row ----------
__global__ __launch_bounds__(256) void combine_kernel(const ushort* __restrict__ Opart,
                                                      const float2* __restrict__ mlbuf,
                                                      ushort* __restrict__ AO) {
  const int gid = blockIdx.x * 4 + (threadIdx.x >> 6);   // [0, 65536) = bh*2048+q
  const int lane = threadIdx.x & 63;
  const int bh = gid >> 11, q = gid & 2047;
  const int qi = q >> 7, np = (qi >> 2) + 1;
  const size_t base = ((size_t)(bh * 16 + qi) * 4) * 128 + (q & 127);

  float M = -INFINITY;
  for (int p = 0; p < np; p++) M = fmaxf(M, mlbuf[base + (size_t)p * 128].x);
  float den = 0.f, acc = 0.f;
  for (int p = 0; p < np; p++) {
    const float2 ml = mlbuf[base + (size_t)p * 128];
    const float wp = exp2f(ml.x - M);
    den += wp * ml.y;
    acc += wp * bf2f(Opart[(base + (size_t)p * 128) * 64 + lane]);
  }
  const float val = acc / den;
  const int bb = bh >> 4, hd = bh & 15;
  AO[((size_t)bb * TSEQ + q) * DMODEL + hd * DK + lane] = f2bf(val);
}

extern "C" void kernel_launch(void* const* d_in, const int* in_sizes, int n_in,
                              void* d_out, int out_size, void* d_ws, size_t ws_size,
                              hipStream_t stream) {
  (void)in_sizes; (void)n_in; (void)out_size; (void)ws_size;
  const float* x    = (const float*)d_in[0];
  const float* Wkqv = (const float*)d_in[1];
  const float* bkqv = (const float*)d_in[2];
  const float* Wo   = (const float*)d_in[3];
  const float* bo   = (const float*)d_in[4];
  float* out = (float*)d_out;

  char* ws = (char*)d_ws;
  const size_t MB = 1024 * 1024;
  ushort* x_bf   = (ushort*)(ws + 0);        //  8 MB [4096][1024]
  ushort* wkqv_t = (ushort*)(ws + 8 * MB);   //  6 MB [3072][1024]
  ushort* wo_t   = (ushort*)(ws + 14 * MB);  //  2 MB [1024][1024]
  ushort* Kbuf   = (ushort*)(ws + 16 * MB);  //  8 MB [32][2048][64]
  ushort* Qbuf   = (ushort*)(ws + 24 * MB);  //  8 MB (pre-scaled by QSCALE)
  ushort* Vtbuf  = (ushort*)(ws + 32 * MB);  //  8 MB [32][64][2048]
  ushort* AObuf  = (ushort*)(ws + 48 * MB);  //  8 MB [4096][1024]
  ushort* Opart  = (ushort*)(ws + 56 * MB);  // 32 MB [32][16][4][128][64]
  float2* mlbuf  = (float2*)(ws + 88 * MB);  //  2 MB [32][16][4][128]

  prep_kernel<<<3072, 256, 0, stream>>>(x, x_bf, Wkqv, wkqv_t, Wo, wo_t);
  gemm_bt_kernel<0><<<dim3(3072 / 128, 4096 / 128), 256, 0, stream>>>(
      x_bf, wkqv_t, bkqv, Kbuf, Qbuf, Vtbuf, nullptr, 3072, 1024);
  attn_kernel<<<1280, 256, 0, stream>>>(Qbuf, Kbuf, Vtbuf, Opart, mlbuf);
  combine_kernel<<<16384, 256, 0, stream>>>(Opart, mlbuf, AObuf);
  gemm_bt_kernel<1><<<dim3(1024 / 128, 4096 / 64), 256, 0, stream>>>(
      AObuf, wo_t, bo, nullptr, nullptr, nullptr, out, 1024, 1024);
}